// Round 13
// baseline (50.930 us; speedup 1.0000x reference)
//
#include <hip/hip_runtime.h>
#include <hip/hip_bf16.h>
#include <math.h>

#define BB 4
#define CC 64
#define OCN 64
#define HH 128
#define WW 128
#define HW (HH*WW)
#define KKN 9
#define APAD 200          // accs row stride x2 bytes (400 B) for phase-C tile

typedef short short8 __attribute__((ext_vector_type(8)));
typedef short short4v __attribute__((ext_vector_type(4)));
typedef float floatx4 __attribute__((ext_vector_type(4)));
typedef float floatx2 __attribute__((ext_vector_type(2)));
typedef unsigned int uintx4 __attribute__((ext_vector_type(4)));

__device__ __forceinline__ float bf2f_us(unsigned short u) {
    return __uint_as_float(((unsigned)u) << 16);
}
__device__ __forceinline__ short f2bfs(float f) {
    __hip_bfloat16 h = __float2bfloat16(f);
    return *reinterpret_cast<short*>(&h);
}
__device__ __forceinline__ uintx4 as_u4(short8 v) {
    union { short8 s; uintx4 u; } x; x.s = v; return x.u;
}
__device__ __forceinline__ float blo(unsigned d) { return __uint_as_float(d << 16); }
__device__ __forceinline__ float bhi(unsigned d) { return __uint_as_float(d & 0xffff0000u); }

// ---------------- transpose_prep: float4 loads, 64 px/block, XOR-swizzled tile --------
__global__ __launch_bounds__(256) void transpose_prep(
    const float* __restrict__ x,
    const float* __restrict__ w_dcn, const float* __restrict__ w_off,
    const float* __restrict__ b_off, const float* __restrict__ w_mask,
    const float* __restrict__ b_mask,
    __hip_bfloat16* __restrict__ xt, __hip_bfloat16* __restrict__ wTf,
    __hip_bfloat16* __restrict__ wOf, float* __restrict__ rebias)
{
    int blk = blockIdx.x;
    int tid = threadIdx.x;
    if (blk < BB * 256) {
        __shared__ float tile[64][64];   // col = p ^ ((c>>3)<<2), 16 KB
        int pixbase = (blk & 255) * 64;
        int b       = blk >> 8;
        const float* xb = x + (size_t)b * CC * HW;
        #pragma unroll
        for (int i = 0; i < 4; ++i) {
            int c  = (tid >> 4) + i * 16;
            int p4 = (tid & 15) * 4;
            floatx4 v = *reinterpret_cast<const floatx4*>(xb + (size_t)c * HW + pixbase + p4);
            int cs = p4 ^ (((c >> 3) & 7) << 2);
            *reinterpret_cast<floatx4*>(&tile[c][cs]) = v;
        }
        __syncthreads();
        __hip_bfloat16* xo = xt + ((size_t)b * HW + pixbase) * CC;
        int c8t = tid & 7;
        #pragma unroll
        for (int i = 0; i < 2; ++i) {
            int pixl = (tid >> 3) + i * 32;
            short8 o;
            #pragma unroll
            for (int j = 0; j < 8; ++j)
                o[j] = f2bfs(tile[c8t * 8 + j][pixl ^ (c8t << 2)]);
            *reinterpret_cast<short8*>(&xo[(size_t)pixl * CC + c8t * 8]) = o;
        }
        return;
    }
    int i = (blk - BB * 256) * 256 + tid;
    if (i < 18 * 4 * 64 * 8) {                 // wTf: 18 K-steps x 4 oc-tiles
        int jj = i & 7;
        int l  = (i >> 3) & 63;
        int nt = (i >> 9) & 3;
        int s  = i >> 11;
        int oc = nt * 16 + (l & 15);
        int kk = s * 32 + ((l >> 4) << 3) + jj;
        int c  = kk & 63;
        int kt = kk >> 6;
        wTf[i] = __float2bfloat16(w_dcn[(oc * CC + c) * 9 + kt]);
    }
    int j = i - 18 * 4 * 64 * 8;
    if (j >= 0 && j < 18 * 2 * 64 * 8) {       // wOf: 18 K-steps x 2 oc-tiles (27 used)
        int jj = j & 7;
        int l  = (j >> 3) & 63;
        int nt = (j >> 9) & 1;
        int s  = j >> 10;
        int oc = nt * 16 + (l & 15);
        int kk = s * 32 + ((l >> 4) << 3) + jj;
        int c  = kk & 63;
        int kt = kk >> 6;
        float v = 0.0f;
        if (oc < 18)      v = w_off[(oc * CC + c) * 9 + kt];
        else if (oc < 27) v = w_mask[((oc - 18) * CC + c) * 9 + kt];
        wOf[j] = __float2bfloat16(v);
    }
    int r = j - 18 * 2 * 64 * 8;
    if (r >= 0 && r < 27) rebias[r] = (r < 18) ? b_off[r] : b_mask[r - 18];
}

// ---------------- deform_fused: 64 px/block, XCD-swizzled --------------------------
// Phase A: 3x3 conv GEMM, A-fragments loaded DIRECTLY from global xt (no LDS, no
//          barriers). Bit-identical values to the staged version.
// Phase B: tap setup from LDS bf16 offsets/mask.
// Phase C: gather, 3-deep double-buffer pipeline + MFMA (wave = oc-tile, 4 pgs).
__global__ __launch_bounds__(256, 4) void deform_fused(
    const __hip_bfloat16* __restrict__ xt,
    const __hip_bfloat16* __restrict__ wTf, const __hip_bfloat16* __restrict__ wOf,
    const float* __restrict__ rebias, const float* __restrict__ b_dcn,
    float* __restrict__ off_out, float* __restrict__ out)
{
    __shared__ __align__(16) char scr[64 * APAD * 2];         // 25600 B (phase-C accs)
    __shared__ uintx4 tabs[KKN][64];                          // 9216 B
    __shared__ __hip_bfloat16 offs_l[18][68];                 // 2448 B
    __shared__ __hip_bfloat16 ms_l[KKN][68];                  // 1224 B

    int tid    = threadIdx.x;
    int lane   = tid & 63;
    int wv     = __builtin_amdgcn_readfirstlane(tid >> 6);
    int lane15 = lane & 15;
    int lq     = lane >> 4;       // 0..3
    int nt     = wv & 1;          // phase-A oc-tile
    int ph     = wv >> 1;         // phase-A pixel-half
    int pix    = tid >> 3;        // 0..31 (gather pixel within half)
    int c8     = tid & 7;         // 0..7
    int co     = c8 * 16;         // byte offset within a pixel's 128B channel row
    int kreg   = lq << 3;

    // XCD-aware bijective swizzle (1024 blocks % 8 XCDs == 0)
    int bid = blockIdx.x;
    int swz = ((bid & 7) << 7) | (bid >> 3);
    int wo0 = (swz & 1) * 64;
    int row = (swz >> 1) & (HH - 1);
    int b   = swz >> 8;

    const char* xtb = (const char*)(xt + (size_t)b * HW * CC);
    const short8* wTf8 = (const short8*)wTf;
    const short8* wOf8 = (const short8*)wOf;
    const short8 zero8 = {0,0,0,0,0,0,0,0};

    // ================= Phase A: 3x3 conv GEMM, direct-global A-frags =================
    floatx4 accomA[2] = {{0,0,0,0},{0,0,0,0}};
    #pragma unroll
    for (int ky = 0; ky < 3; ++ky) {
        int y = row + ky - 1;
        bool yv = (unsigned)y < (unsigned)HH;
        int yc = min(max(y, 0), HH - 1);
        short8 af[2][6];
        #pragma unroll
        for (int s6 = 0; s6 < 6; ++s6) {
            int kx = s6 >> 1;
            int colb = (s6 & 1) * 64 + lq * 16;     // channel-byte offset of this frag
            #pragma unroll
            for (int q = 0; q < 2; ++q) {
                int pg = ph * 2 + q;
                int xw = wo0 + pg * 16 + lane15 + kx - 1;
                bool v = yv && ((unsigned)xw < (unsigned)WW);
                int xc = min(max(xw, 0), WW - 1);
                short8 t = *(const short8*)(xtb + (((yc * WW) + xc) << 7) + colb);
                af[q][s6] = v ? t : zero8;
            }
        }
        #pragma unroll
        for (int s6 = 0; s6 < 6; ++s6) {
            int s = ky * 6 + s6;
            short8 bfrag = wOf8[(size_t)(s * 2 + nt) * 64 + lane];
            accomA[0] = __builtin_amdgcn_mfma_f32_16x16x32_bf16(af[0][s6], bfrag, accomA[0], 0, 0, 0);
            accomA[1] = __builtin_amdgcn_mfma_f32_16x16x32_bf16(af[1][s6], bfrag, accomA[1], 0, 0, 0);
        }
    }

    // epilogue A: offsets -> global (f32) + LDS bf16; sigmoid(mask) -> LDS bf16
    #pragma unroll
    for (int q = 0; q < 2; ++q) {
        int pg = ph * 2 + q;
        int pcl = pg * 16 + lq * 4;
        int oc = nt * 16 + lane15;
        if (oc < 18) {
            float bias = rebias[oc];
            floatx4 o = accomA[q];
            o[0] += bias; o[1] += bias; o[2] += bias; o[3] += bias;
            *reinterpret_cast<floatx4*>(
                &off_out[(((size_t)b * 18 + oc) * HH + row) * WW + wo0 + pcl]) = o;
            short4v ob = { f2bfs(o[0]), f2bfs(o[1]), f2bfs(o[2]), f2bfs(o[3]) };
            *reinterpret_cast<short4v*>(&offs_l[oc][pcl]) = ob;
        } else if (oc < 27) {
            float bias = rebias[oc];
            short4v mb;
            #pragma unroll
            for (int t = 0; t < 4; ++t)
                mb[t] = f2bfs(1.0f / (1.0f + expf(-(accomA[q][t] + bias))));
            *reinterpret_cast<short4v*>(&ms_l[oc - 18][pcl]) = mb;
        }
    }
    __syncthreads();

    // ================= Phase B: bilinear tap setup (9 k x 64 px) =================
    for (int e = tid; e < KKN * 64; e += 256) {
        int k = e >> 6, p = e & 63;
        float dy = bf2f_us(*(const unsigned short*)&offs_l[2 * k][p]);
        float dx = bf2f_us(*(const unsigned short*)&offs_l[2 * k + 1][p]);
        float m  = bf2f_us(*(const unsigned short*)&ms_l[k][p]);
        float py = dy + (float)(k / 3) + (float)(row - 1);
        float px = dx + (float)(k % 3) + (float)(wo0 + p - 1);
        float y0f = floorf(py), x0f = floorf(px);
        float ly = py - y0f, lx = px - x0f;
        int y0 = (int)y0f, x0 = (int)x0f;
        uintx4 rec;
        #pragma unroll
        for (int t = 0; t < 4; ++t) {
            int yi = y0 + (t >> 1), xi = x0 + (t & 1);
            float wy = (t >> 1) ? ly : 1.0f - ly;
            float wx = (t & 1)  ? lx : 1.0f - lx;
            bool valid = ((unsigned)yi < (unsigned)HH) && ((unsigned)xi < (unsigned)WW);
            int yc2 = min(max(yi, 0), HH - 1);
            int xc2 = min(max(xi, 0), WW - 1);
            __hip_bfloat16 hw = __float2bfloat16(valid ? wy * wx * m : 0.0f);
            unsigned short wb = *reinterpret_cast<unsigned short*>(&hw);
            rec[t] = (unsigned)(yc2 * WW + xc2) | ((unsigned)wb << 16);
        }
        tabs[k][p] = rec;
    }
    __syncthreads();

    // ================= Phase C: gather (18 groups, 3-deep dbuf) + MFMA GEMM ==========
    short8 buf[3][4];
    uintx4 tb[3];
    floatx4 accv[4] = {{0,0,0,0},{0,0,0,0},{0,0,0,0},{0,0,0,0}};

#define ACCS(PIX, COLB) (scr + (PIX) * (APAD * 2) + (COLB))

#define ISSUE(G) do { \
    uintx4 _t = tabs[(G) >> 1][pix + ((G) & 1) * 32]; \
    tb[(G) % 3] = _t; \
    buf[(G) % 3][0] = *(const short8*)(xtb + ((_t[0] & 0xffffu) << 7) + co); \
    buf[(G) % 3][1] = *(const short8*)(xtb + ((_t[1] & 0xffffu) << 7) + co); \
    buf[(G) % 3][2] = *(const short8*)(xtb + ((_t[2] & 0xffffu) << 7) + co); \
    buf[(G) % 3][3] = *(const short8*)(xtb + ((_t[3] & 0xffffu) << 7) + co); \
} while (0)

#define COMBINE(G) do { \
    floatx2 f2[4] = {{0,0},{0,0},{0,0},{0,0}}; \
    _Pragma("unroll") \
    for (int t = 0; t < 4; ++t) { \
        float wt = __uint_as_float(tb[(G) % 3][t] & 0xffff0000u); \
        floatx2 wt2 = {wt, wt}; \
        uintx4 dA = as_u4(buf[(G) % 3][t]); \
        _Pragma("unroll") \
        for (int jq = 0; jq < 4; ++jq) { \
            floatx2 xv = { blo(dA[jq]), bhi(dA[jq]) }; \
            f2[jq] = __builtin_elementwise_fma(wt2, xv, f2[jq]); \
        } \
    } \
    short8 oA; \
    _Pragma("unroll") \
    for (int jq = 0; jq < 4; ++jq) { \
        oA[2 * jq]     = f2bfs(f2[jq][0]); \
        oA[2 * jq + 1] = f2bfs(f2[jq][1]); \
    } \
    *(short8*)ACCS(((G) & 1) * 32 + pix, (((G) >> 1) % 3) * 128 + c8 * 16) = oA; \
} while (0)

#define CMFMA(CH) do { \
    _Pragma("unroll") \
    for (int step = 0; step < 6; ++step) { \
        int s = (CH) * 6 + step; \
        short8 bfrag = wTf8[(size_t)(s * 4 + wv) * 64 + lane]; \
        _Pragma("unroll") \
        for (int pg = 0; pg < 4; ++pg) { \
            short8 a = *(const short8*)ACCS(pg * 16 + lane15, step * 64 + kreg * 2); \
            accv[pg] = __builtin_amdgcn_mfma_f32_16x16x32_bf16(a, bfrag, accv[pg], 0, 0, 0); \
        } \
    } \
} while (0)

    ISSUE(0); ISSUE(1); ISSUE(2);
    COMBINE(0); ISSUE(3);
    COMBINE(1); ISSUE(4);
    COMBINE(2); ISSUE(5);
    COMBINE(3); ISSUE(6);           // groups 6..8 prefetched, fly across MFMA+barrier
    COMBINE(4); ISSUE(7);
    COMBINE(5); ISSUE(8);
    __syncthreads();
    CMFMA(0);
    asm volatile("s_waitcnt lgkmcnt(0)" ::: "memory");
    __builtin_amdgcn_s_barrier();   // raw: does NOT drain vmcnt
    COMBINE(6); ISSUE(9);
    COMBINE(7); ISSUE(10);
    COMBINE(8); ISSUE(11);
    COMBINE(9); ISSUE(12);
    COMBINE(10); ISSUE(13);
    COMBINE(11); ISSUE(14);
    __syncthreads();
    CMFMA(1);
    asm volatile("s_waitcnt lgkmcnt(0)" ::: "memory");
    __builtin_amdgcn_s_barrier();
    COMBINE(12); ISSUE(15);
    COMBINE(13); ISSUE(16);
    COMBINE(14); ISSUE(17);
    COMBINE(15); COMBINE(16); COMBINE(17);
    __syncthreads();
    CMFMA(2);

#undef ISSUE
#undef COMBINE
#undef CMFMA
#undef ACCS

    // epilogue C: wave wv owns oc-tile wv; D: col=lane15 (oc), row=lq*4+reg (pixel)
    {
        int oc = wv * 16 + lane15;
        float bias = b_dcn[oc];
        #pragma unroll
        for (int pg = 0; pg < 4; ++pg) {
            int pcol = wo0 + pg * 16 + lq * 4;
            floatx4 o = accv[pg];
            o[0] += bias; o[1] += bias; o[2] += bias; o[3] += bias;
            *reinterpret_cast<floatx4*>(&out[(((size_t)b * OCN + oc) * HH + row) * WW + pcol]) = o;
        }
    }
}

extern "C" void kernel_launch(void* const* d_in, const int* in_sizes, int n_in,
                              void* d_out, int out_size, void* d_ws, size_t ws_size,
                              hipStream_t stream) {
    const float* x      = (const float*)d_in[0];
    const float* w_off  = (const float*)d_in[1];
    const float* b_off  = (const float*)d_in[2];
    const float* w_mask = (const float*)d_in[3];
    const float* b_mask = (const float*)d_in[4];
    const float* w_dcn  = (const float*)d_in[5];
    const float* b_dcn  = (const float*)d_in[6];

    float* out     = (float*)d_out;                       // B*OC*H*W
    float* off_out = out + (size_t)BB * OCN * HW;         // B*18*H*W (output 1)

    float* rebias  = (float*)d_ws;                        // 32 f32
    __hip_bfloat16* xt  = (__hip_bfloat16*)(rebias + 32); // B*HW*C bf16
    __hip_bfloat16* wTf = xt + (size_t)BB * HW * CC;      // 18*4*64*8 bf16
    __hip_bfloat16* wOf = wTf + 18 * 4 * 64 * 8;          // 18*2*64*8 bf16

    int prep_total  = 18 * 4 * 64 * 8 + 18 * 2 * 64 * 8 + 27;
    int prep_blocks = (prep_total + 255) / 256;           // 217
    transpose_prep<<<BB * 256 + prep_blocks, 256, 0, stream>>>(
        x, w_dcn, w_off, b_off, w_mask, b_mask, xt, wTf, wOf, rebias);

    deform_fused<<<BB * HH * 2, 256, 0, stream>>>(
        xt, wTf, wOf, rebias, b_dcn, off_out, out);
}

// Round 14
// 38.078 us; speedup vs baseline: 1.3375x; 1.3375x over previous
//
#include <hip/hip_runtime.h>
#include <hip/hip_bf16.h>
#include <math.h>

#define BB 4
#define CC 64
#define OCN 64
#define HH 128
#define WW 128
#define HW (HH*WW)
#define KKN 9
#define APAD 200          // accs row stride x2 bytes (400 B) for phase-C tile
#define RSTRIDE 144       // raw-row stride in bytes (64ch*2B + 16B pad)
#define SLOTSZ (66*RSTRIDE)  // 9504 B per raw-row slot

typedef short short8 __attribute__((ext_vector_type(8)));
typedef short short4v __attribute__((ext_vector_type(4)));
typedef float floatx4 __attribute__((ext_vector_type(4)));
typedef float floatx2 __attribute__((ext_vector_type(2)));
typedef unsigned int uintx4 __attribute__((ext_vector_type(4)));

__device__ __forceinline__ float bf2f_us(unsigned short u) {
    return __uint_as_float(((unsigned)u) << 16);
}
__device__ __forceinline__ short f2bfs(float f) {
    __hip_bfloat16 h = __float2bfloat16(f);
    return *reinterpret_cast<short*>(&h);
}
__device__ __forceinline__ uintx4 as_u4(short8 v) {
    union { short8 s; uintx4 u; } x; x.s = v; return x.u;
}
__device__ __forceinline__ float blo(unsigned d) { return __uint_as_float(d << 16); }
__device__ __forceinline__ float bhi(unsigned d) { return __uint_as_float(d & 0xffff0000u); }

// ---------------- transpose_prep: float4 loads, 64 px/block, XOR-swizzled tile (= R13) -
__global__ __launch_bounds__(256) void transpose_prep(
    const float* __restrict__ x,
    const float* __restrict__ w_dcn, const float* __restrict__ w_off,
    const float* __restrict__ b_off, const float* __restrict__ w_mask,
    const float* __restrict__ b_mask,
    __hip_bfloat16* __restrict__ xt, __hip_bfloat16* __restrict__ wTf,
    __hip_bfloat16* __restrict__ wOf, float* __restrict__ rebias)
{
    int blk = blockIdx.x;
    int tid = threadIdx.x;
    if (blk < BB * 256) {
        __shared__ float tile[64][64];   // col = p ^ ((c>>3)<<2), 16 KB
        int pixbase = (blk & 255) * 64;
        int b       = blk >> 8;
        const float* xb = x + (size_t)b * CC * HW;
        #pragma unroll
        for (int i = 0; i < 4; ++i) {
            int c  = (tid >> 4) + i * 16;
            int p4 = (tid & 15) * 4;
            floatx4 v = *reinterpret_cast<const floatx4*>(xb + (size_t)c * HW + pixbase + p4);
            int cs = p4 ^ (((c >> 3) & 7) << 2);
            *reinterpret_cast<floatx4*>(&tile[c][cs]) = v;
        }
        __syncthreads();
        __hip_bfloat16* xo = xt + ((size_t)b * HW + pixbase) * CC;
        int c8t = tid & 7;
        #pragma unroll
        for (int i = 0; i < 2; ++i) {
            int pixl = (tid >> 3) + i * 32;
            short8 o;
            #pragma unroll
            for (int j = 0; j < 8; ++j)
                o[j] = f2bfs(tile[c8t * 8 + j][pixl ^ (c8t << 2)]);
            *reinterpret_cast<short8*>(&xo[(size_t)pixl * CC + c8t * 8]) = o;
        }
        return;
    }
    int i = (blk - BB * 256) * 256 + tid;
    if (i < 18 * 4 * 64 * 8) {                 // wTf: 18 K-steps x 4 oc-tiles
        int jj = i & 7;
        int l  = (i >> 3) & 63;
        int nt = (i >> 9) & 3;
        int s  = i >> 11;
        int oc = nt * 16 + (l & 15);
        int kk = s * 32 + ((l >> 4) << 3) + jj;
        int c  = kk & 63;
        int kt = kk >> 6;
        wTf[i] = __float2bfloat16(w_dcn[(oc * CC + c) * 9 + kt]);
    }
    int j = i - 18 * 4 * 64 * 8;
    if (j >= 0 && j < 18 * 2 * 64 * 8) {       // wOf: 18 K-steps x 2 oc-tiles (27 used)
        int jj = j & 7;
        int l  = (j >> 3) & 63;
        int nt = (j >> 9) & 1;
        int s  = j >> 10;
        int oc = nt * 16 + (l & 15);
        int kk = s * 32 + ((l >> 4) << 3) + jj;
        int c  = kk & 63;
        int kt = kk >> 6;
        float v = 0.0f;
        if (oc < 18)      v = w_off[(oc * CC + c) * 9 + kt];
        else if (oc < 27) v = w_mask[((oc - 18) * CC + c) * 9 + kt];
        wOf[j] = __float2bfloat16(v);
    }
    int r = j - 18 * 2 * 64 * 8;
    if (r >= 0 && r < 27) rebias[r] = (r < 18) ? b_off[r] : b_mask[r - 18];
}

// ---------------- deform_fused: 64 px/block, XCD-swizzled -----------------------------
// Phase A: 3x3 conv GEMM; halo rows staged ONCE as [66][64ch] LDS slots (= R12,
//          coalesced 8 lanes/line), A-frags read shifted. Bit-identical math.
// Phase B: tap setup from LDS bf16 offsets/mask.
// Phase C: gather, 3-deep pipeline + pk_fma COMBINE + MFMA (= R13).
__global__ __launch_bounds__(256, 4) void deform_fused(
    const __hip_bfloat16* __restrict__ xt,
    const __hip_bfloat16* __restrict__ wTf, const __hip_bfloat16* __restrict__ wOf,
    const float* __restrict__ rebias, const float* __restrict__ b_dcn,
    float* __restrict__ off_out, float* __restrict__ out)
{
    __shared__ __align__(16) char scr[64 * APAD * 2];         // 25600 B (A raw rows / C accs)
    __shared__ uintx4 tabs[KKN][64];                          // 9216 B
    __shared__ __hip_bfloat16 offs_l[18][68];                 // 2448 B
    __shared__ __hip_bfloat16 ms_l[KKN][68];                  // 1224 B

    int tid    = threadIdx.x;
    int lane   = tid & 63;
    int wv     = __builtin_amdgcn_readfirstlane(tid >> 6);
    int lane15 = lane & 15;
    int lq     = lane >> 4;       // 0..3
    int nt     = wv & 1;          // phase-A oc-tile
    int ph     = wv >> 1;         // phase-A pixel-half
    int pix    = tid >> 3;        // 0..31 (gather pixel within half)
    int c8     = tid & 7;         // 0..7
    int co     = c8 * 16;         // byte offset within a pixel's 128B channel row
    int kreg   = lq << 3;

    // XCD-aware bijective swizzle (1024 blocks % 8 XCDs == 0)
    int bid = blockIdx.x;
    int swz = ((bid & 7) << 7) | (bid >> 3);
    int wo0 = (swz & 1) * 64;
    int row = (swz >> 1) & (HH - 1);
    int b   = swz >> 8;

    const char* xtb = (const char*)(xt + (size_t)b * HW * CC);
    const short8* wTf8 = (const short8*)wTf;
    const short8* wOf8 = (const short8*)wOf;
    const short8 zero8 = {0,0,0,0,0,0,0,0};

    // ================= Phase A: 3x3 conv GEMM, raw-row LDS staging (= R12) ============
    floatx4 accomA[2] = {{0,0,0,0},{0,0,0,0}};

#define STAGE_ROW(KY, SLOT) do { \
    int _y = row + (KY) - 1; \
    bool _yv = (unsigned)_y < (unsigned)HH; \
    int _yc = min(max(_y, 0), HH - 1); \
    _Pragma("unroll") \
    for (int _it = 0; _it < 3; ++_it) { \
        int _e = tid + _it * 256; \
        if (_e < 528) { \
            int _px66 = _e >> 3, _c8 = _e & 7; \
            int _xw = wo0 + _px66 - 1; \
            bool _v = _yv && ((unsigned)_xw < (unsigned)WW); \
            int _xc = min(max(_xw, 0), WW - 1); \
            short8 _t = *(const short8*)(xtb + (((_yc * WW) + _xc) << 7) + _c8 * 16); \
            if (!_v) _t = zero8; \
            *(short8*)(scr + (SLOT) * SLOTSZ + _px66 * RSTRIDE + _c8 * 16) = _t; \
        } \
    } \
} while (0)

#define AMFMA(KY, SLOT) do { \
    _Pragma("unroll") \
    for (int s6 = 0; s6 < 6; ++s6) { \
        int s = (KY) * 6 + s6; \
        int kx = s6 >> 1; \
        short8 bfrag = wOf8[(size_t)(s * 2 + nt) * 64 + lane]; \
        _Pragma("unroll") \
        for (int q = 0; q < 2; ++q) { \
            int pg = ph * 2 + q; \
            short8 a = *(const short8*)(scr + (SLOT) * SLOTSZ \
                + (pg * 16 + lane15 + kx) * RSTRIDE + (s6 & 1) * 64 + lq * 16); \
            accomA[q] = __builtin_amdgcn_mfma_f32_16x16x32_bf16(a, bfrag, accomA[q], 0, 0, 0); \
        } \
    } \
} while (0)

    STAGE_ROW(0, 0);
    __syncthreads();
    STAGE_ROW(1, 1);        // loads fly over chunk-0 MFMAs
    AMFMA(0, 0);
    __syncthreads();
    STAGE_ROW(2, 0);
    AMFMA(1, 1);
    __syncthreads();
    AMFMA(2, 0);

#undef STAGE_ROW
#undef AMFMA

    // epilogue A: offsets -> global (f32) + LDS bf16; sigmoid(mask) -> LDS bf16
    #pragma unroll
    for (int q = 0; q < 2; ++q) {
        int pg = ph * 2 + q;
        int pcl = pg * 16 + lq * 4;
        int oc = nt * 16 + lane15;
        if (oc < 18) {
            float bias = rebias[oc];
            floatx4 o = accomA[q];
            o[0] += bias; o[1] += bias; o[2] += bias; o[3] += bias;
            *reinterpret_cast<floatx4*>(
                &off_out[(((size_t)b * 18 + oc) * HH + row) * WW + wo0 + pcl]) = o;
            short4v ob = { f2bfs(o[0]), f2bfs(o[1]), f2bfs(o[2]), f2bfs(o[3]) };
            *reinterpret_cast<short4v*>(&offs_l[oc][pcl]) = ob;
        } else if (oc < 27) {
            float bias = rebias[oc];
            short4v mb;
            #pragma unroll
            for (int t = 0; t < 4; ++t)
                mb[t] = f2bfs(1.0f / (1.0f + expf(-(accomA[q][t] + bias))));
            *reinterpret_cast<short4v*>(&ms_l[oc - 18][pcl]) = mb;
        }
    }
    __syncthreads();

    // ================= Phase B: bilinear tap setup (9 k x 64 px) =================
    for (int e = tid; e < KKN * 64; e += 256) {
        int k = e >> 6, p = e & 63;
        float dy = bf2f_us(*(const unsigned short*)&offs_l[2 * k][p]);
        float dx = bf2f_us(*(const unsigned short*)&offs_l[2 * k + 1][p]);
        float m  = bf2f_us(*(const unsigned short*)&ms_l[k][p]);
        float py = dy + (float)(k / 3) + (float)(row - 1);
        float px = dx + (float)(k % 3) + (float)(wo0 + p - 1);
        float y0f = floorf(py), x0f = floorf(px);
        float ly = py - y0f, lx = px - x0f;
        int y0 = (int)y0f, x0 = (int)x0f;
        uintx4 rec;
        #pragma unroll
        for (int t = 0; t < 4; ++t) {
            int yi = y0 + (t >> 1), xi = x0 + (t & 1);
            float wy = (t >> 1) ? ly : 1.0f - ly;
            float wx = (t & 1)  ? lx : 1.0f - lx;
            bool valid = ((unsigned)yi < (unsigned)HH) && ((unsigned)xi < (unsigned)WW);
            int yc2 = min(max(yi, 0), HH - 1);
            int xc2 = min(max(xi, 0), WW - 1);
            __hip_bfloat16 hw = __float2bfloat16(valid ? wy * wx * m : 0.0f);
            unsigned short wb = *reinterpret_cast<unsigned short*>(&hw);
            rec[t] = (unsigned)(yc2 * WW + xc2) | ((unsigned)wb << 16);
        }
        tabs[k][p] = rec;
    }
    __syncthreads();

    // ================= Phase C: gather (18 groups, 3-deep dbuf) + MFMA GEMM ==========
    short8 buf[3][4];
    uintx4 tb[3];
    floatx4 accv[4] = {{0,0,0,0},{0,0,0,0},{0,0,0,0},{0,0,0,0}};

#define ACCS(PIX, COLB) (scr + (PIX) * (APAD * 2) + (COLB))

#define ISSUE(G) do { \
    uintx4 _t = tabs[(G) >> 1][pix + ((G) & 1) * 32]; \
    tb[(G) % 3] = _t; \
    buf[(G) % 3][0] = *(const short8*)(xtb + ((_t[0] & 0xffffu) << 7) + co); \
    buf[(G) % 3][1] = *(const short8*)(xtb + ((_t[1] & 0xffffu) << 7) + co); \
    buf[(G) % 3][2] = *(const short8*)(xtb + ((_t[2] & 0xffffu) << 7) + co); \
    buf[(G) % 3][3] = *(const short8*)(xtb + ((_t[3] & 0xffffu) << 7) + co); \
} while (0)

#define COMBINE(G) do { \
    floatx2 f2[4] = {{0,0},{0,0},{0,0},{0,0}}; \
    _Pragma("unroll") \
    for (int t = 0; t < 4; ++t) { \
        float wt = __uint_as_float(tb[(G) % 3][t] & 0xffff0000u); \
        floatx2 wt2 = {wt, wt}; \
        uintx4 dA = as_u4(buf[(G) % 3][t]); \
        _Pragma("unroll") \
        for (int jq = 0; jq < 4; ++jq) { \
            floatx2 xv = { blo(dA[jq]), bhi(dA[jq]) }; \
            f2[jq] = __builtin_elementwise_fma(wt2, xv, f2[jq]); \
        } \
    } \
    short8 oA; \
    _Pragma("unroll") \
    for (int jq = 0; jq < 4; ++jq) { \
        oA[2 * jq]     = f2bfs(f2[jq][0]); \
        oA[2 * jq + 1] = f2bfs(f2[jq][1]); \
    } \
    *(short8*)ACCS(((G) & 1) * 32 + pix, (((G) >> 1) % 3) * 128 + c8 * 16) = oA; \
} while (0)

#define CMFMA(CH) do { \
    _Pragma("unroll") \
    for (int step = 0; step < 6; ++step) { \
        int s = (CH) * 6 + step; \
        short8 bfrag = wTf8[(size_t)(s * 4 + wv) * 64 + lane]; \
        _Pragma("unroll") \
        for (int pg = 0; pg < 4; ++pg) { \
            short8 a = *(const short8*)ACCS(pg * 16 + lane15, step * 64 + kreg * 2); \
            accv[pg] = __builtin_amdgcn_mfma_f32_16x16x32_bf16(a, bfrag, accv[pg], 0, 0, 0); \
        } \
    } \
} while (0)

    ISSUE(0); ISSUE(1); ISSUE(2);
    COMBINE(0); ISSUE(3);
    COMBINE(1); ISSUE(4);
    COMBINE(2); ISSUE(5);
    COMBINE(3); ISSUE(6);           // groups 6..8 prefetched, fly across MFMA+barrier
    COMBINE(4); ISSUE(7);
    COMBINE(5); ISSUE(8);
    __syncthreads();
    CMFMA(0);
    asm volatile("s_waitcnt lgkmcnt(0)" ::: "memory");
    __builtin_amdgcn_s_barrier();   // raw: does NOT drain vmcnt
    COMBINE(6); ISSUE(9);
    COMBINE(7); ISSUE(10);
    COMBINE(8); ISSUE(11);
    COMBINE(9); ISSUE(12);
    COMBINE(10); ISSUE(13);
    COMBINE(11); ISSUE(14);
    __syncthreads();
    CMFMA(1);
    asm volatile("s_waitcnt lgkmcnt(0)" ::: "memory");
    __builtin_amdgcn_s_barrier();
    COMBINE(12); ISSUE(15);
    COMBINE(13); ISSUE(16);
    COMBINE(14); ISSUE(17);
    COMBINE(15); COMBINE(16); COMBINE(17);
    __syncthreads();
    CMFMA(2);

#undef ISSUE
#undef COMBINE
#undef CMFMA
#undef ACCS

    // epilogue C: wave wv owns oc-tile wv; D: col=lane15 (oc), row=lq*4+reg (pixel)
    {
        int oc = wv * 16 + lane15;
        float bias = b_dcn[oc];
        #pragma unroll
        for (int pg = 0; pg < 4; ++pg) {
            int pcol = wo0 + pg * 16 + lq * 4;
            floatx4 o = accv[pg];
            o[0] += bias; o[1] += bias; o[2] += bias; o[3] += bias;
            *reinterpret_cast<floatx4*>(&out[(((size_t)b * OCN + oc) * HH + row) * WW + pcol]) = o;
        }
    }
}

extern "C" void kernel_launch(void* const* d_in, const int* in_sizes, int n_in,
                              void* d_out, int out_size, void* d_ws, size_t ws_size,
                              hipStream_t stream) {
    const float* x      = (const float*)d_in[0];
    const float* w_off  = (const float*)d_in[1];
    const float* b_off  = (const float*)d_in[2];
    const float* w_mask = (const float*)d_in[3];
    const float* b_mask = (const float*)d_in[4];
    const float* w_dcn  = (const float*)d_in[5];
    const float* b_dcn  = (const float*)d_in[6];

    float* out     = (float*)d_out;                       // B*OC*H*W
    float* off_out = out + (size_t)BB * OCN * HW;         // B*18*H*W (output 1)

    float* rebias  = (float*)d_ws;                        // 32 f32
    __hip_bfloat16* xt  = (__hip_bfloat16*)(rebias + 32); // B*HW*C bf16
    __hip_bfloat16* wTf = xt + (size_t)BB * HW * CC;      // 18*4*64*8 bf16
    __hip_bfloat16* wOf = wTf + 18 * 4 * 64 * 8;          // 18*2*64*8 bf16

    int prep_total  = 18 * 4 * 64 * 8 + 18 * 2 * 64 * 8 + 27;
    int prep_blocks = (prep_total + 255) / 256;           // 217
    transpose_prep<<<BB * 256 + prep_blocks, 256, 0, stream>>>(
        x, w_dcn, w_off, b_off, w_mask, b_mask, xt, wTf, wOf, rebias);

    deform_fused<<<BB * HH * 2, 256, 0, stream>>>(
        xt, wTf, wOf, rebias, b_dcn, off_out, out);
}